// Round 6
// baseline (342.471 us; speedup 1.0000x reference)
//
#include <hip/hip_runtime.h>
#include <hip/hip_bf16.h>

#define B_    32
#define C_    128
#define H_    56
#define W_    56
#define OUT_  256
#define K_    4
#define HID_  64
#define HW_   (H_*W_)        // 3136
#define KV_   (C_*9)         // 1152
#define PH_   58
#define PW_   58
#define PP_   (PH_*PW_)      // 3364 padded pixels per sample

typedef __attribute__((ext_vector_type(8))) short short8_t;   // 8 x bf16
typedef __attribute__((ext_vector_type(4))) float float4_t;

typedef __hip_bfloat16 bf16;

__device__ __forceinline__ short f2bf(float v) {
    union { bf16 h; short s; } u; u.h = __float2bfloat16(v); return u.s;
}

typedef __attribute__((address_space(1))) const unsigned int* gas_t;
typedef __attribute__((address_space(3))) unsigned int* las_t;

// async global->LDS, 16 B per lane; LDS dest = wave-uniform base + lane*16
__device__ __forceinline__ void gl_lds16(const short* g, short* l) {
    __builtin_amdgcn_global_load_lds((gas_t)(const void*)g, (las_t)(void*)l, 16, 0, 0);
}

// ---------------------------------------------------------------------------
// Kernel 1 (fused): blocks [0, B_*C_)        -> global avg pool (sums)
//                   blocks [B_*C_, +27*B_)   -> pad-transpose x -> xTp
// Fusing the two INDEPENDENT front kernels into one grid-partitioned launch
// removes one full launch+drain from the 5-deep dependent chain.
// ---------------------------------------------------------------------------
__global__ __launch_bounds__(256) void dc_px(const float* __restrict__ x,
                                             short* __restrict__ xTp,
                                             float* __restrict__ pooled) {
    __shared__ short t[C_][130];     // xt part (33 KB)
    __shared__ float ps[4];          // pool part
    int idx = blockIdx.x;

    if (idx < B_*C_) {
        // ---- pool part: one block per (b,c) ----
        const float4_t* xp = (const float4_t*)(x + (size_t)idx * HW_);
        float s = 0.f;
        for (int j = threadIdx.x; j < HW_/4; j += 256) {   // 784 float4
            float4_t v = xp[j];
            s += v[0] + v[1] + v[2] + v[3];
        }
        #pragma unroll
        for (int off = 32; off; off >>= 1) s += __shfl_down(s, off, 64);
        if ((threadIdx.x & 63) == 0) ps[threadIdx.x >> 6] = s;
        __syncthreads();
        if (threadIdx.x == 0) pooled[idx] = ps[0] + ps[1] + ps[2] + ps[3];
        return;
    }

    // ---- pad-transpose part ----
    int xb = idx - B_*C_;            // 0..863
    int b = xb / 27, nchunk = xb - b*27;
    int n0 = nchunk * 128;
    for (int i = threadIdx.x; i < C_*128; i += 256) {
        int c = i >> 7, nn = i & 127;
        int pp = n0 + nn;
        int py = pp / PW_, px = pp - py*PW_;
        bool valid = (pp < PP_) & (py >= 1) & (py <= H_) & (px >= 1) & (px <= W_);
        float v = valid ? x[((size_t)b*C_ + c)*HW_ + (py-1)*W_ + (px-1)] : 0.f;
        t[c][nn] = f2bf(v);
    }
    __syncthreads();
    typedef __attribute__((ext_vector_type(2))) unsigned int uint2_t;
    for (int i = threadIdx.x; i < 32*128; i += 256) {
        int nn = i >> 5, c4 = (i & 31) * 4;
        int pp = n0 + nn;
        if (pp < PP_) {
            union { unsigned short u[4]; uint2_t v; } pk;
            pk.u[0] = (unsigned short)t[c4  ][nn];
            pk.u[1] = (unsigned short)t[c4+1][nn];
            pk.u[2] = (unsigned short)t[c4+2][nn];
            pk.u[3] = (unsigned short)t[c4+3][nn];
            *(uint2_t*)&xTp[((size_t)b*PP_ + pp)*C_ + c4] = pk.v;
        }
    }
}

// ---------------------------------------------------------------------------
// Kernel 2 (fused): weight synthesis with INLINE attention recompute.
// grid (OUT_, 4): block = (o, group of 8 samples). Each block computes the
// attention vectors for its 8 samples from `pooled` (a few K redundant FMAs
// per block; fc1w stays L2-hot) -- removes the 32-block dc_attn dispatch
// that idled the whole GPU between launches.
// ---------------------------------------------------------------------------
__global__ __launch_bounds__(256) void dc_wsattn(const float* __restrict__ bank,
                                                 const float* __restrict__ pooled,
                                                 const float* __restrict__ fc1w,
                                                 const float* __restrict__ fc1b,
                                                 const float* __restrict__ fc2w,
                                                 const float* __restrict__ fc2b,
                                                 bf16* __restrict__ Ws) {
    int o = blockIdx.x;
    int b0 = blockIdx.y * 8;
    int tid = threadIdx.x;
    __shared__ float wb[4*KV_];          // 18 KB
    __shared__ float pl[8][C_];          // 4 KB
    __shared__ float hdnl[8][HID_];      // 2 KB
    __shared__ float attn_l[8][K_];      // 128 B

    // stage bank rows for this o (vectorized float4: 1152 float4)
    const float4_t* bk4 = (const float4_t*)bank;
    float4_t* wb4 = (float4_t*)wb;
    for (int i = tid; i < KV_; i += 256) {           // KV_ float4 = 4*KV_ floats
        int kk = i / 288, r = i - kk*288;            // 288 float4 per (kk,o) row
        wb4[i] = bk4[((size_t)kk*OUT_ + o)*288 + r];
    }
    // stage pooled (pre-scaled by 1/HW)
    for (int i = tid; i < 8*C_; i += 256)
        pl[i >> 7][i & 127] = pooled[(size_t)(b0 + (i >> 7))*C_ + (i & 127)] * (1.0f/HW_);
    __syncthreads();

    // hdn[bi][h] for 8 samples x 64 h = 512 over 256 threads (2 rounds)
    #pragma unroll
    for (int r = 0; r < 2; ++r) {
        int p = r*256 + tid;
        int bi = p >> 6, h = p & 63;
        float s = fc1b[h];
        #pragma unroll 8
        for (int c = 0; c < C_; ++c) s += pl[bi][c] * fc1w[h*C_ + c];
        hdnl[bi][h] = fmaxf(s, 0.f);
    }
    __syncthreads();

    // logits + softmax: 32 threads, quad of lanes per sample
    if (tid < 32) {
        int bi = tid >> 2, k = tid & 3;
        float t0 = fc2b[k];
        #pragma unroll 8
        for (int j = 0; j < HID_; ++j) t0 += hdnl[bi][j] * fc2w[k*HID_ + j];
        float m = t0;
        m = fmaxf(m, __shfl_xor(m, 1, 64));
        m = fmaxf(m, __shfl_xor(m, 2, 64));
        float e = __expf(t0 - m);
        float se = e;
        se += __shfl_xor(se, 1, 64);
        se += __shfl_xor(se, 2, 64);
        attn_l[bi][k] = e / se;
    }
    __syncthreads();

    // synthesis (same inner loop as the proven dc_wsynth)
    for (int bi = 0; bi < 8; ++bi) {
        int b = b0 + bi;
        float a0 = attn_l[bi][0], a1 = attn_l[bi][1];
        float a2 = attn_l[bi][2], a3 = attn_l[bi][3];
        unsigned* dst = (unsigned*)&Ws[((size_t)b*OUT_ + o)*KV_];
        for (int ii = tid; ii < KV_/2; ii += 256) {
            int i0 = 2*ii;
            int tap0 = i0 >> 7, c0 = i0 & 127;
            int i1 = i0 + 1;
            int tap1 = i1 >> 7, c1 = i1 & 127;
            float v0 = a0*wb[c0*9+tap0] + a1*wb[KV_+c0*9+tap0]
                     + a2*wb[2*KV_+c0*9+tap0] + a3*wb[3*KV_+c0*9+tap0];
            float v1 = a0*wb[c1*9+tap1] + a1*wb[KV_+c1*9+tap1]
                     + a2*wb[2*KV_+c1*9+tap1] + a3*wb[3*KV_+c1*9+tap1];
            union { unsigned short u[2]; unsigned v; } pk;
            pk.u[0] = (unsigned short)f2bf(v0);
            pk.u[1] = (unsigned short)f2bf(v1);
            dst[ii] = pk.v;
        }
    }
}

// ---------------------------------------------------------------------------
// Kernel 3: LDS-staged implicit GEMM (m97 structure, BK=64) — exact round-0
// version. Measured 150.1-150.4 us twice (rounds 0 & 3); all four structural
// variants (BK=64 dbuf 192, zero-LDS 260, BK=32 dbuf 158, counted-vmcnt 158)
// regressed. No swizzle: the no-swizzle variant was consistently fastest
// (L3 absorbs the re-fetch; swizzle's extra index math costs more than it
// saves here).
// ---------------------------------------------------------------------------
__global__ __launch_bounds__(256) void dc_gemm(const short* __restrict__ Ws,
                                               const short* __restrict__ xTp,
                                               float* __restrict__ out) {
    const int b  = blockIdx.z;
    const int m0 = blockIdx.y * 128;
    const int n0 = blockIdx.x * 128;
    const int tid  = threadIdx.x;
    const int lane = tid & 63;
    const int wv   = tid >> 6;
    const int wm   = wv & 1, wn = wv >> 1;
    const int l16  = lane & 15, quad = lane >> 4;

    __shared__ short lA[128*64];   // 16 KB
    __shared__ short lB[128*64];   // 16 KB

    // --- staging source pointers: wave wv stages segments t = 4*wv + j ---
    const short* aG[4];
    const short* bG[4];
    short* aL[4];
    short* bL[4];
    #pragma unroll
    for (int j = 0; j < 4; ++j) {
        int t = 4*wv + j;
        int row = (t >> 1) * 16 + l16;
        int kq  = t & 1;
        aG[j] = Ws + ((size_t)b*OUT_ + m0 + row)*KV_ + kq*32 + quad*8;
        int n = n0 + row;
        int idc = min(n, HW_ - 1);
        int y = idc / W_, xx2 = idc - y * W_;
        int pbc = (y + 1) * PW_ + (xx2 + 1);
        bG[j] = xTp + ((size_t)b*PP_ + pbc)*C_ + kq*32 + quad*8;
        aL[j] = lA + t*512;
        bL[j] = lB + t*512;
    }

    int nidx[4];
    #pragma unroll
    for (int ni = 0; ni < 4; ++ni)
        nidx[ni] = n0 + wn*64 + ni*16 + l16;

    float4_t acc[4][4];
    #pragma unroll
    for (int mi = 0; mi < 4; ++mi)
        #pragma unroll
        for (int ni = 0; ni < 4; ++ni)
            acc[mi][ni] = (float4_t){0.f, 0.f, 0.f, 0.f};

    for (int tap = 0; tap < 9; ++tap) {
        int ty = tap / 3, tx = tap - 3*ty;
        int doff = (ty - 1) * PW_ + (tx - 1);
        #pragma unroll
        for (int half = 0; half < 2; ++half) {
            const int kk = tap*128 + half*64;   // A column base
            const int cc = half*64;             // B column base
            #pragma unroll
            for (int j = 0; j < 4; ++j) {
                gl_lds16(aG[j] + kk, aL[j]);
                gl_lds16(bG[j] + doff*C_ + cc, bL[j]);
            }
            __syncthreads();                    // drains vmcnt(0), publishes LDS
            #pragma unroll
            for (int kq = 0; kq < 2; ++kq) {
                short8_t af[4], bf[4];
                #pragma unroll
                for (int mi = 0; mi < 4; ++mi)
                    af[mi] = *(const short8_t*)(lA + ((wm*4+mi)*2 + kq)*512 + lane*8);
                #pragma unroll
                for (int ni = 0; ni < 4; ++ni)
                    bf[ni] = *(const short8_t*)(lB + ((wn*4+ni)*2 + kq)*512 + lane*8);
                #pragma unroll
                for (int mi = 0; mi < 4; ++mi)
                    #pragma unroll
                    for (int ni = 0; ni < 4; ++ni)
                        acc[mi][ni] = __builtin_amdgcn_mfma_f32_16x16x32_bf16(
                            af[mi], bf[ni], acc[mi][ni], 0, 0, 0);
            }
            __syncthreads();                    // all reads done before next overwrite
        }
    }

    // Epilogue: D[m = quad*4 + reg][n = l16] per 16x16 tile
    const size_t obase = (size_t)b * OUT_ * HW_;
    #pragma unroll
    for (int mi = 0; mi < 4; ++mi) {
        int m = m0 + wm*64 + mi*16 + quad*4;
        #pragma unroll
        for (int ni = 0; ni < 4; ++ni) {
            int n = nidx[ni];
            if (n < HW_) {
                float* op = out + obase + (size_t)m * HW_ + n;
                #pragma unroll
                for (int r = 0; r < 4; ++r)
                    op[(size_t)r * HW_] = acc[mi][ni][r];
            }
        }
    }
}

// ---------------------------------------------------------------------------
extern "C" void kernel_launch(void* const* d_in, const int* in_sizes, int n_in,
                              void* d_out, int out_size, void* d_ws, size_t ws_size,
                              hipStream_t stream) {
    const float* x    = (const float*)d_in[0];
    const float* bank = (const float*)d_in[1];
    const float* fc1w = (const float*)d_in[2];
    const float* fc1b = (const float*)d_in[3];
    const float* fc2w = (const float*)d_in[4];
    const float* fc2b = (const float*)d_in[5];
    float* out = (float*)d_out;

    char* ws = (char*)d_ws;
    float* pooled = (float*)ws;                          // 16 KB
    bf16*  Ws     = (bf16*) (ws + 32*1024);              // 18,874,368 B
    short* xTp    = (short*)(ws + 32*1024 + 18874368);   // 27,557,888 B

    dc_px    <<<B_*C_ + 27*B_, 256, 0, stream>>>(x, xTp, pooled);
    dc_wsattn<<<dim3(OUT_, 4), 256, 0, stream>>>(bank, pooled, fc1w, fc1b,
                                                 fc2w, fc2b, Ws);
    dc_gemm  <<<dim3(25, 2, B_), 256, 0, stream>>>((const short*)Ws, xTp, out);
}

// Round 7
// 319.992 us; speedup vs baseline: 1.0702x; 1.0702x over previous
//
#include <hip/hip_runtime.h>
#include <hip/hip_bf16.h>

#define B_    32
#define C_    128
#define H_    56
#define W_    56
#define OUT_  256
#define K_    4
#define HID_  64
#define HW_   (H_*W_)        // 3136
#define KV_   (C_*9)         // 1152
#define PH_   58
#define PW_   58
#define PP_   (PH_*PW_)      // 3364 padded pixels per sample

typedef __attribute__((ext_vector_type(8))) short short8_t;   // 8 x bf16
typedef __attribute__((ext_vector_type(4))) float float4_t;

typedef __hip_bfloat16 bf16;

__device__ __forceinline__ short f2bf(float v) {
    union { bf16 h; short s; } u; u.h = __float2bfloat16(v); return u.s;
}

typedef __attribute__((address_space(1))) const unsigned int* gas_t;
typedef __attribute__((address_space(3))) unsigned int* las_t;

// async global->LDS, 16 B per lane; LDS dest = wave-uniform base + lane*16
__device__ __forceinline__ void gl_lds16(const short* g, short* l) {
    __builtin_amdgcn_global_load_lds((gas_t)(const void*)g, (las_t)(void*)l, 16, 0, 0);
}

// ---------------------------------------------------------------------------
// Kernel 0: global avg pool (sums; dc_attn divides by HW). Separate launch:
// tiny LDS -> 8 blocks/CU (round-6 fusion forced 33KB LDS on it -> regressed).
// ---------------------------------------------------------------------------
__global__ __launch_bounds__(256) void dc_pool(const float* __restrict__ x,
                                               float* __restrict__ pooled) {
    int bc = blockIdx.x;                       // b*C_ + c
    const float4_t* xp = (const float4_t*)(x + (size_t)bc * HW_);
    float s = 0.f;
    for (int j = threadIdx.x; j < HW_/4; j += 256) {   // 784 float4
        float4_t v = xp[j];
        s += v[0] + v[1] + v[2] + v[3];
    }
    #pragma unroll
    for (int off = 32; off; off >>= 1) s += __shfl_down(s, off, 64);
    __shared__ float ps[4];
    if ((threadIdx.x & 63) == 0) ps[threadIdx.x >> 6] = s;
    __syncthreads();
    if (threadIdx.x == 0) pooled[bc] = ps[0] + ps[1] + ps[2] + ps[3];
}

// ---------------------------------------------------------------------------
// Kernel 1: pure pad-transpose  x -> zero-padded xTp[b][58*58][c] (bf16).
// ---------------------------------------------------------------------------
__global__ __launch_bounds__(256) void dc_xt(const float* __restrict__ x,
                                             short* __restrict__ xTp) {
    int b = blockIdx.y, n0 = blockIdx.x * 128;   // 27 x-blocks cover 3456 >= 3364
    __shared__ short t[C_][130];
    for (int i = threadIdx.x; i < C_*128; i += 256) {
        int c = i >> 7, nn = i & 127;
        int pp = n0 + nn;
        int py = pp / PW_, px = pp - py*PW_;
        bool valid = (pp < PP_) & (py >= 1) & (py <= H_) & (px >= 1) & (px <= W_);
        float v = valid ? x[((size_t)b*C_ + c)*HW_ + (py-1)*W_ + (px-1)] : 0.f;
        t[c][nn] = f2bf(v);
    }
    __syncthreads();
    typedef __attribute__((ext_vector_type(2))) unsigned int uint2_t;
    for (int i = threadIdx.x; i < 32*128; i += 256) {
        int nn = i >> 5, c4 = (i & 31) * 4;
        int pp = n0 + nn;
        if (pp < PP_) {
            union { unsigned short u[4]; uint2_t v; } pk;
            pk.u[0] = (unsigned short)t[c4  ][nn];
            pk.u[1] = (unsigned short)t[c4+1][nn];
            pk.u[2] = (unsigned short)t[c4+2][nn];
            pk.u[3] = (unsigned short)t[c4+3][nn];
            *(uint2_t*)&xTp[((size_t)b*PP_ + pp)*C_ + c4] = pk.v;
        }
    }
}

// ---------------------------------------------------------------------------
// Kernel 2: attn = softmax(relu((pooled/HW)@fc1^T)@fc2^T)
// ---------------------------------------------------------------------------
__global__ __launch_bounds__(64) void dc_attn(const float* __restrict__ pooled,
                                              const float* __restrict__ fc1w,
                                              const float* __restrict__ fc1b,
                                              const float* __restrict__ fc2w,
                                              const float* __restrict__ fc2b,
                                              float* __restrict__ attn) {
    int b = blockIdx.x, h = threadIdx.x;
    __shared__ float pl[C_];
    __shared__ float hdn[HID_];
    __shared__ float logit[K_];
    pl[h]      = pooled[b*C_ + h]      * (1.0f / HW_);
    pl[h + 64] = pooled[b*C_ + 64 + h] * (1.0f / HW_);
    __syncthreads();
    float s = fc1b[h];
    #pragma unroll 8
    for (int c = 0; c < C_; ++c) s += pl[c] * fc1w[h*C_ + c];
    hdn[h] = fmaxf(s, 0.f);
    __syncthreads();
    if (h < K_) {
        float t = fc2b[h];
        #pragma unroll 8
        for (int j = 0; j < HID_; ++j) t += hdn[j] * fc2w[h*HID_ + j];
        logit[h] = t;
    }
    __syncthreads();
    if (h == 0) {
        float m = fmaxf(fmaxf(logit[0], logit[1]), fmaxf(logit[2], logit[3]));
        float e0 = __expf(logit[0]-m), e1 = __expf(logit[1]-m);
        float e2 = __expf(logit[2]-m), e3 = __expf(logit[3]-m);
        float inv = 1.0f / (e0+e1+e2+e3);
        attn[b*K_+0]=e0*inv; attn[b*K_+1]=e1*inv;
        attn[b*K_+2]=e2*inv; attn[b*K_+3]=e3*inv;
    }
}

// ---------------------------------------------------------------------------
// Kernel 3: weight synthesis  Ws[b][o][k=tap*128+c] (bf16)
// ---------------------------------------------------------------------------
__global__ __launch_bounds__(256) void dc_wsynth(const float* __restrict__ bank,
                                                 const float* __restrict__ attn,
                                                 bf16* __restrict__ Ws) {
    int o = blockIdx.x;
    int b0 = blockIdx.y * 8;
    __shared__ float wb[4*KV_];
    for (int i = threadIdx.x; i < 4*KV_; i += 256) {
        int kk = i / KV_, r = i - kk*KV_;
        wb[i] = bank[((size_t)kk*OUT_ + o)*KV_ + r];
    }
    __syncthreads();
    for (int bi = 0; bi < 8; ++bi) {
        int b = b0 + bi;
        float a0 = attn[b*K_+0], a1 = attn[b*K_+1];
        float a2 = attn[b*K_+2], a3 = attn[b*K_+3];
        unsigned* dst = (unsigned*)&Ws[((size_t)b*OUT_ + o)*KV_];
        for (int ii = threadIdx.x; ii < KV_/2; ii += 256) {
            int i0 = 2*ii;
            int tap0 = i0 >> 7, c0 = i0 & 127;
            int i1 = i0 + 1;
            int tap1 = i1 >> 7, c1 = i1 & 127;
            float v0 = a0*wb[c0*9+tap0] + a1*wb[KV_+c0*9+tap0]
                     + a2*wb[2*KV_+c0*9+tap0] + a3*wb[3*KV_+c0*9+tap0];
            float v1 = a0*wb[c1*9+tap1] + a1*wb[KV_+c1*9+tap1]
                     + a2*wb[2*KV_+c1*9+tap1] + a3*wb[3*KV_+c1*9+tap1];
            union { unsigned short u[2]; unsigned v; } pk;
            pk.u[0] = (unsigned short)f2bf(v0);
            pk.u[1] = (unsigned short)f2bf(v1);
            dst[ii] = pk.v;
        }
    }
}

// ---------------------------------------------------------------------------
// Kernel 4: implicit GEMM, DEEP-PREFETCH pipeline (T3+T4 proper).
// Rounds 1/2/4/5 isolated the failure modes: drain-to-0 barriers (r0/r1/r4),
// no MLP engine (r2), counted-vmcnt WITHOUT phase interleave (r5 = m218's
// null quadrant). This is the measured-positive mechanism: 4 rotating
// buffers (depth-3 prefetch, 12 loads/wave in flight), ONE barrier per
// 32-k sub-step, vmcnt NEVER drained to 0 in the loop, stage-issue
// sandwiched between ds_read and MFMA (m196's required fine interleave),
// setprio around the MFMA cluster (T5).
// Safety: each wave's ds_reads retire before its MFMAs (compiler lgkmcnt),
// hence before the barrier; barrier@ss therefore proves (a) everyone's
// buf(ss) loads landed (each waited own vmcnt first), (b) everyone's
// buf(ss-1) reads retired -> stage(ss+3) may overwrite buf((ss+3)&3) =
// buf((ss-1)&3).  Tail: vmcnt(4)@34, vmcnt(0)@35.
// LDS 64 KB -> 2 blocks/CU; bank conflicts 0 by fragment-ordered layout.
// ---------------------------------------------------------------------------
__global__ __launch_bounds__(256) void dc_gemm(const short* __restrict__ Ws,
                                               const short* __restrict__ xTp,
                                               float* __restrict__ out) {
    const int b  = blockIdx.z;
    const int m0 = blockIdx.y * 128;
    const int n0 = blockIdx.x * 128;
    const int tid  = threadIdx.x;
    const int lane = tid & 63;
    const int wv   = tid >> 6;
    const int wm   = wv & 1, wn = wv >> 1;
    const int l16  = lane & 15, quad = lane >> 4;

    __shared__ short lA[4][4096];   // 4 x 8 KB
    __shared__ short lB[4][4096];   // 4 x 8 KB   (64 KB total)

    // wave wv stages regions t = 2*wv + j (j=0,1): rows t*16+l16, col quad*8
    const short* aG[2];
    const short* bG[2];
    int tOff[2];
    #pragma unroll
    for (int j = 0; j < 2; ++j) {
        int t = 2*wv + j;
        int row = t*16 + l16;
        aG[j] = Ws + ((size_t)b*OUT_ + m0 + row)*KV_ + quad*8;
        int n = n0 + row;
        int idc = min(n, HW_ - 1);
        int y = idc / W_, xx2 = idc - y * W_;
        int pbc = (y + 1) * PW_ + (xx2 + 1);
        bG[j] = xTp + ((size_t)b*PP_ + pbc)*C_ + quad*8;
        tOff[j] = t * 512;
    }

    int nidx[4];
    #pragma unroll
    for (int ni = 0; ni < 4; ++ni)
        nidx[ni] = n0 + wn*64 + ni*16 + l16;

    float4_t acc[4][4];
    #pragma unroll
    for (int mi = 0; mi < 4; ++mi)
        #pragma unroll
        for (int ni = 0; ni < 4; ++ni)
            acc[mi][ni] = (float4_t){0.f, 0.f, 0.f, 0.f};

    // stage sub-step ss (= tap*4 + kq2, 36 total) into buffer buf.
    // ka = tap*128 + (ss&3)*32 = ss*32; tap/3 via magic-mul.
    auto stage = [&](int ss, int buf) {
        int tap = ss >> 2;
        int ty  = (tap * 11) >> 5;               // == tap/3 for tap in [0,8]
        int tx  = tap - 3 * ty;
        int doff = ((ty - 1) * PW_ + (tx - 1)) * C_;
        int ka = ss * 32;
        int cb = (ss & 3) * 32;
        #pragma unroll
        for (int j = 0; j < 2; ++j) {
            gl_lds16(aG[j] + ka,        &lA[buf][tOff[j]]);
            gl_lds16(bG[j] + doff + cb, &lB[buf][tOff[j]]);
        }
    };

    // Prologue: depth-3 prefetch (12 loads/wave in flight).
    stage(0, 0);
    stage(1, 1);
    stage(2, 2);

    #pragma unroll 1
    for (int ss = 0; ss < 36; ++ss) {
        const int buf = ss & 3;
        // wait ONLY the oldest sub-step's 4 loads; 8 newer stay in flight
        if (ss < 34)       asm volatile("s_waitcnt vmcnt(8)" ::: "memory");
        else if (ss == 34) asm volatile("s_waitcnt vmcnt(4)" ::: "memory");
        else               asm volatile("s_waitcnt vmcnt(0)" ::: "memory");
        __builtin_amdgcn_s_barrier();

        short8_t af[4], bfr[4];
        #pragma unroll
        for (int mi = 0; mi < 4; ++mi)
            af[mi] = *(const short8_t*)(&lA[buf][(wm*4+mi)*512 + lane*8]);
        #pragma unroll
        for (int ni = 0; ni < 4; ++ni)
            bfr[ni] = *(const short8_t*)(&lB[buf][(wn*4+ni)*512 + lane*8]);

        // issue the depth-3 prefetch between ds_read and MFMA (fine interleave)
        if (ss + 3 < 36) stage(ss + 3, (ss + 3) & 3);

        __builtin_amdgcn_s_setprio(1);
        #pragma unroll
        for (int mi = 0; mi < 4; ++mi)
            #pragma unroll
            for (int ni = 0; ni < 4; ++ni)
                acc[mi][ni] = __builtin_amdgcn_mfma_f32_16x16x32_bf16(
                    af[mi], bfr[ni], acc[mi][ni], 0, 0, 0);
        __builtin_amdgcn_s_setprio(0);
    }

    // Epilogue: D[m = quad*4 + reg][n = l16] per 16x16 tile
    const size_t obase = (size_t)b * OUT_ * HW_;
    #pragma unroll
    for (int mi = 0; mi < 4; ++mi) {
        int m = m0 + wm*64 + mi*16 + quad*4;
        #pragma unroll
        for (int ni = 0; ni < 4; ++ni) {
            int n = nidx[ni];
            if (n < HW_) {
                float* op = out + obase + (size_t)m * HW_ + n;
                #pragma unroll
                for (int r = 0; r < 4; ++r)
                    op[(size_t)r * HW_] = acc[mi][ni][r];
            }
        }
    }
}

// ---------------------------------------------------------------------------
extern "C" void kernel_launch(void* const* d_in, const int* in_sizes, int n_in,
                              void* d_out, int out_size, void* d_ws, size_t ws_size,
                              hipStream_t stream) {
    const float* x    = (const float*)d_in[0];
    const float* bank = (const float*)d_in[1];
    const float* fc1w = (const float*)d_in[2];
    const float* fc1b = (const float*)d_in[3];
    const float* fc2w = (const float*)d_in[4];
    const float* fc2b = (const float*)d_in[5];
    float* out = (float*)d_out;

    char* ws = (char*)d_ws;
    float* pooled = (float*)ws;                          // 16 KB
    float* attn   = (float*)(ws + 16*1024);              // 512 B
    bf16*  Ws     = (bf16*) (ws + 32*1024);              // 18,874,368 B
    short* xTp    = (short*)(ws + 32*1024 + 18874368);   // 27,557,888 B

    dc_pool  <<<B_*C_, 256, 0, stream>>>(x, pooled);
    dc_xt    <<<dim3(27, B_), 256, 0, stream>>>(x, xTp);
    dc_attn  <<<B_,     64, 0, stream>>>(pooled, fc1w, fc1b, fc2w, fc2b, attn);
    dc_wsynth<<<dim3(OUT_, 4), 256, 0, stream>>>(bank, attn, Ws);
    dc_gemm  <<<dim3(25, 2, B_), 256, 0, stream>>>((const short*)Ws, xTp, out);
}